// Round 1
// baseline (544.366 us; speedup 1.0000x reference)
//
#include <hip/hip_runtime.h>
#include <math.h>

#define NBIN 25
#define T 256       // threads per block
#define PAD 27      // 25 bins + 1 label-count slot, padded to 27 (coprime with 32 banks)
#define CHUNKS 64   // blocks per batch

// ws layout per batch b (stride 64 floats):
//   [0..24]  num_per_bin (sum sa*label)
//   [25..49] den_per_bin (sum sa)
//   [50]     label sum

__global__ __launch_bounds__(256)
void qap_accum(const float* __restrict__ qX, const float* __restrict__ dXs,
               const int* __restrict__ labels, float* __restrict__ ws, int N) {
    __shared__ float q[128];
    __shared__ float accN[T * PAD];
    __shared__ float accD[T * PAD];
    __shared__ float part[4 * 64];

    const int tid   = threadIdx.x;
    const int b     = blockIdx.x / CHUNKS;
    const int chunk = blockIdx.x % CHUNKS;

    if (tid < 128) q[tid] = qX[b * 128 + tid];
    for (int i = tid; i < T * PAD; i += T) { accN[i] = 0.f; accD[i] = 0.f; }
    __syncthreads();

    // query norm (redundant per thread, broadcast LDS reads, once per block)
    float qs = 0.f;
    #pragma unroll 8
    for (int j = 0; j < 128; ++j) qs = fmaf(q[j], q[j], qs);
    const float qn = fmaxf(sqrtf(qs), 1e-8f);

    const int per = (N + CHUNKS - 1) / CHUNKS;
    const int n0 = chunk * per;
    const int n1 = (n0 + per < N) ? (n0 + per) : N;

    const float4* q4 = reinterpret_cast<const float4*>(q);
    const int base = tid * PAD;
    float labCnt = 0.f;

    for (int n = n0 + tid; n < n1; n += T) {
        const float4* row =
            reinterpret_cast<const float4*>(dXs + ((size_t)b * N + n) * 128);
        float dot = 0.f, nrm = 0.f;
        #pragma unroll
        for (int j = 0; j < 32; ++j) {
            float4 x  = row[j];
            float4 qv = q4[j];
            dot = fmaf(x.x, qv.x, dot); dot = fmaf(x.y, qv.y, dot);
            dot = fmaf(x.z, qv.z, dot); dot = fmaf(x.w, qv.w, dot);
            nrm = fmaf(x.x, x.x, nrm);  nrm = fmaf(x.y, x.y, nrm);
            nrm = fmaf(x.z, x.z, nrm);  nrm = fmaf(x.w, x.w, nrm);
        }
        const float dn  = fmaxf(sqrtf(nrm), 1e-8f);
        const float sim = dot / (qn * dn);
        float p = (1.0f - sim) * 12.0f;          // 1/DELTA = (NBIN-1)/2 = 12
        p = fminf(fmaxf(p, 0.0f), 24.0f);
        int m = (int)p;
        if (m > 24) m = 24;
        const float frac = p - (float)m;
        const float lab  = (float)labels[(size_t)b * N + n];
        labCnt += lab;
        const float w0 = 1.0f - frac;
        accD[base + m] += w0;
        accN[base + m] += lab * w0;
        if (m + 1 < NBIN) {
            accD[base + m + 1] += frac;
            accN[base + m + 1] += lab * frac;
        }
    }
    accD[base + 25] = labCnt;
    __syncthreads();

    // block reduction: 51 columns (0..24 num, 25..49 den, 50 labelSum), 4-way split
    const int c  = tid & 63;
    const int qd = tid >> 6;
    if (c < 51) {
        const int idx = (c < 25) ? c : ((c < 50) ? (c - 25) : 25);
        const float* arr = (c < 25) ? accN : accD;
        float s = 0.f;
        const int t0 = qd * 64;
        #pragma unroll 8
        for (int t = t0; t < t0 + 64; ++t) s += arr[t * PAD + idx];
        part[qd * 64 + c] = s;
    }
    __syncthreads();
    if (tid < 51) {
        const float s = part[tid] + part[64 + tid] + part[128 + tid] + part[192 + tid];
        atomicAdd(&ws[b * 64 + tid], s);
    }
}

__global__ void qap_final(const float* __restrict__ ws, float* __restrict__ out, int B) {
    const int lane = threadIdx.x;
    float ap = 0.f;
    if (lane < B) {
        const float* w = ws + lane * 64;
        const float labSum = w[50];
        float cn = 0.f, cd = 0.f;
        for (int k = 0; k < NBIN; ++k) {
            const float nk = w[k];
            const float dk = w[25 + k];
            cn += nk;
            cd += dk;
            const float prec = cn / (1e-16f + cd);   // pDen / pNum per reference
            const float rec  = nk / labSum;
            ap = fmaf(prec, rec, ap);
        }
    }
    for (int off = 32; off > 0; off >>= 1) ap += __shfl_down(ap, off);
    if (lane == 0) out[0] = ap / (float)B;
}

extern "C" void kernel_launch(void* const* d_in, const int* in_sizes, int n_in,
                              void* d_out, int out_size, void* d_ws, size_t ws_size,
                              hipStream_t stream) {
    const float* qX     = (const float*)d_in[0];
    const float* dXs    = (const float*)d_in[1];
    const int*   labels = (const int*)d_in[2];
    float* out = (float*)d_out;
    float* ws  = (float*)d_ws;

    const int M = in_sizes[1] / in_sizes[2];      // 128
    const int B = in_sizes[0] / M;                // 16
    const int N = in_sizes[2] / B;                // 50000
    (void)M;

    hipMemsetAsync(ws, 0, (size_t)B * 64 * sizeof(float), stream);
    qap_accum<<<B * CHUNKS, T, 0, stream>>>(qX, dXs, labels, ws, N);
    qap_final<<<1, 64, 0, stream>>>(ws, out, B);
}